// Round 17
// baseline (2646.398 us; speedup 1.0000x reference)
//
#include <hip/hip_runtime.h>

#define DM 768
#define SCAN_BS 1024

using u16 = unsigned short;
using u32 = unsigned int;

typedef __attribute__((ext_vector_type(8))) __bf16 bf16x8;
typedef __attribute__((ext_vector_type(4))) float f32x4;
typedef __attribute__((address_space(1))) void gvoid;
typedef __attribute__((address_space(3))) void lvoid;

__device__ __forceinline__ float bf2f(u16 h) { return __uint_as_float(((u32)h) << 16); }
__device__ __forceinline__ u16 f2bf(float f) {
    u32 u = __float_as_uint(f);
    u32 r = (u + 0x7FFFu + ((u >> 16) & 1u)) >> 16;
    return (u16)r;
}
// tanh-form GELU (max |err| vs exact erf-GELU ~1e-3): cheap v_exp + rcp
__device__ __forceinline__ float gelu_f(float x) {
    float y = 0.7978845608f * x * (1.f + 0.044715f * x * x);
    float e = __expf(2.f * y);
    float th = 1.f - 2.f * __builtin_amdgcn_rcpf(e + 1.f);   // tanh(y), inf-safe
    return 0.5f * x * (1.f + th);
}

// ---------------- weight prep: W[768,768] f32 -> Wt[768,768] bf16 (transposed) ----------------
__global__ __launch_bounds__(256) void prep_weights(
    const float* __restrict__ aw1, const float* __restrict__ aw2,
    const float* __restrict__ bw1, const float* __restrict__ bw2,
    const float* __restrict__ cw1, const float* __restrict__ cw2,
    u16* __restrict__ wbt)
{
    int z = blockIdx.z;
    const float* W;
    if (z == 0) W = aw1;
    else if (z == 1) W = aw2;
    else if (z == 2) W = bw1;
    else if (z == 3) W = bw2;
    else if (z < 8) W = cw1 + (size_t)(z - 4) * DM * DM;
    else W = cw2 + (size_t)(z - 8) * DM * DM;
    u16* out = wbt + (size_t)z * DM * DM;

    __shared__ float tile[32][33];
    int bx = blockIdx.x * 32, by = blockIdx.y * 32;
    int tx = threadIdx.x & 31, ty = threadIdx.x >> 5;
    #pragma unroll
    for (int i = ty; i < 32; i += 8) tile[i][tx] = W[(size_t)(by + i) * DM + bx + tx];
    __syncthreads();
    #pragma unroll
    for (int i = ty; i < 32; i += 8) out[(size_t)(bx + i) * DM + by + tx] = f2bf(tile[tx][i]);
}

// ---------------- atom embedding (nf=9, vocab=64 hard-coded): sum + LN -> bf16 ----------------
__global__ __launch_bounds__(192) void encode_ln9(
    const int* __restrict__ idx,
    const float* __restrict__ emb, const float* __restrict__ g, const float* __restrict__ bb,
    u16* __restrict__ out)
{
    long n = blockIdx.x;
    int t = threadIdx.x;            // 192 threads x 4 cols
    int d = t * 4;
    __shared__ int feat[12];
    __shared__ float sred[8];
    if (t < 9) feat[t] = idx[n * 9 + t];
    __syncthreads();
    float a0 = 0.f, a1 = 0.f, a2 = 0.f, a3 = 0.f;
    #pragma unroll
    for (int f = 0; f < 9; f++) {
        const float* rp = emb + (size_t)f * 64 * DM + (size_t)feat[f] * DM + d;
        float4 v = *reinterpret_cast<const float4*>(rp);
        a0 += v.x; a1 += v.y; a2 += v.z; a3 += v.w;
    }
    float s = a0 + a1 + a2 + a3;
    float s2 = a0 * a0 + a1 * a1 + a2 * a2 + a3 * a3;
    #pragma unroll
    for (int o = 32; o; o >>= 1) { s += __shfl_down(s, o); s2 += __shfl_down(s2, o); }
    int wid = t >> 6;
    if ((t & 63) == 0) { sred[wid] = s; sred[4 + wid] = s2; }
    __syncthreads();
    float S = sred[0] + sred[1] + sred[2];
    float S2 = sred[4] + sred[5] + sred[6];
    float mean = S * (1.f / 768.f);
    float var = S2 * (1.f / 768.f) - mean * mean;
    float rstd = rsqrtf(var + 1e-5f);
    ushort4 o;
    o.x = f2bf((a0 - mean) * rstd * g[d + 0] + bb[d + 0]);
    o.y = f2bf((a1 - mean) * rstd * g[d + 1] + bb[d + 1]);
    o.z = f2bf((a2 - mean) * rstd * g[d + 2] + bb[d + 2]);
    o.w = f2bf((a3 - mean) * rstd * g[d + 3] + bb[d + 3]);
    *reinterpret_cast<ushort4*>(out + n * DM + d) = o;
}

// ---------------- bond table: all 512 key combos, emb-sum + LN -> bf16 ----------------
__global__ __launch_bounds__(256) void encode_ln_bond(
    const float* __restrict__ emb, const float* __restrict__ g, const float* __restrict__ bb,
    u16* __restrict__ out)
{
    int key = blockIdx.x;       // 0..511
    int t = threadIdx.x;
    __shared__ float sred[16];
    int f0 = key & 7, f1 = (key >> 3) & 7, f2 = (key >> 6) & 7;
    float v[3];
    float s = 0.f, s2 = 0.f;
    #pragma unroll
    for (int j = 0; j < 3; j++) {
        int d = t + j * 256;
        float a = emb[(0 * 8 + f0) * DM + d] + emb[(1 * 8 + f1) * DM + d] + emb[(2 * 8 + f2) * DM + d];
        v[j] = a; s += a; s2 += a * a;
    }
    #pragma unroll
    for (int o = 32; o; o >>= 1) { s += __shfl_down(s, o); s2 += __shfl_down(s2, o); }
    int wid = t >> 6;
    if ((t & 63) == 0) { sred[wid] = s; sred[8 + wid] = s2; }
    __syncthreads();
    if (t == 0) {
        sred[0] = sred[0] + sred[1] + sred[2] + sred[3];
        sred[8] = sred[8] + sred[9] + sred[10] + sred[11];
    }
    __syncthreads();
    float mean = sred[0] * (1.f / 768.f);
    float var = sred[8] * (1.f / 768.f) - mean * mean;
    float rstd = rsqrtf(var + 1e-5f);
    #pragma unroll
    for (int j = 0; j < 3; j++) {
        int d = t + j * 256;
        out[(long)key * DM + d] = f2bf((v[j] - mean) * rstd * g[d] + bb[d]);
    }
}

// ---------------- post-layer: t = y(bf16) + h_old(bf16); LN; write h_b OR final f32 out ----------------
__global__ __launch_bounds__(192) void layer_ln(
    const u16* __restrict__ y, const u16* __restrict__ holdb,
    const float* __restrict__ g, const float* __restrict__ bb,
    u16* __restrict__ hb, float* __restrict__ dout)
{
    long n = blockIdx.x;
    int t = threadIdx.x;           // 192 threads x 4 cols = 768
    int d = t * 4;
    __shared__ float sred[8];
    ushort4 yv = *reinterpret_cast<const ushort4*>(y + n * DM + d);
    ushort4 hv = *reinterpret_cast<const ushort4*>(holdb + n * DM + d);
    float v0 = bf2f(yv.x) + bf2f(hv.x);
    float v1 = bf2f(yv.y) + bf2f(hv.y);
    float v2 = bf2f(yv.z) + bf2f(hv.z);
    float v3 = bf2f(yv.w) + bf2f(hv.w);
    float s = v0 + v1 + v2 + v3;
    float s2 = v0 * v0 + v1 * v1 + v2 * v2 + v3 * v3;
    #pragma unroll
    for (int o = 32; o; o >>= 1) { s += __shfl_down(s, o); s2 += __shfl_down(s2, o); }
    int wid = t >> 6;
    if ((t & 63) == 0) { sred[wid] = s; sred[4 + wid] = s2; }
    __syncthreads();
    float S = sred[0] + sred[1] + sred[2];
    float S2 = sred[4] + sred[5] + sred[6];
    float mean = S * (1.f / 768.f);
    float var = S2 * (1.f / 768.f) - mean * mean;
    float rstd = rsqrtf(var + 1e-5f);
    float r0 = (v0 - mean) * rstd * g[d + 0] + bb[d + 0];
    float r1 = (v1 - mean) * rstd * g[d + 1] + bb[d + 1];
    float r2 = (v2 - mean) * rstd * g[d + 2] + bb[d + 2];
    float r3 = (v3 - mean) * rstd * g[d + 3] + bb[d + 3];
    if (dout) {
        float4 o = { r0, r1, r2, r3 };
        *reinterpret_cast<float4*>(dout + n * DM + d) = o;
    } else {
        ushort4 o;
        o.x = f2bf(r0); o.y = f2bf(r1); o.z = f2bf(r2); o.w = f2bf(r3);
        *reinterpret_cast<ushort4*>(hb + n * DM + d) = o;
    }
}

// ---------------- CSR build: counting sort of edges by dst ----------------
__global__ __launch_bounds__(256) void csr_count(const int* __restrict__ dst, int* __restrict__ deg, int E)
{
    int e = blockIdx.x * 256 + threadIdx.x;
    if (e < E) atomicAdd(&deg[dst[e]], 1);
}

__global__ __launch_bounds__(SCAN_BS) void scan_block(const int* __restrict__ deg, int* __restrict__ tmp,
                                                      int* __restrict__ bsum, int n)
{
    __shared__ int sh[SCAN_BS];
    int gid = blockIdx.x * SCAN_BS + threadIdx.x;
    int v = (gid < n) ? deg[gid] : 0;
    sh[threadIdx.x] = v;
    __syncthreads();
    for (int o = 1; o < SCAN_BS; o <<= 1) {
        int add = (threadIdx.x >= o) ? sh[threadIdx.x - o] : 0;
        __syncthreads();
        sh[threadIdx.x] += add;
        __syncthreads();
    }
    if (gid < n) tmp[gid] = sh[threadIdx.x];
    if (threadIdx.x == SCAN_BS - 1) bsum[blockIdx.x] = sh[SCAN_BS - 1];
}

__global__ __launch_bounds__(SCAN_BS) void scan_bsum(int* __restrict__ bsum, int nb)
{
    __shared__ int sh[SCAN_BS];
    int v = (threadIdx.x < nb) ? bsum[threadIdx.x] : 0;
    sh[threadIdx.x] = v;
    __syncthreads();
    for (int o = 1; o < SCAN_BS; o <<= 1) {
        int add = (threadIdx.x >= o) ? sh[threadIdx.x - o] : 0;
        __syncthreads();
        sh[threadIdx.x] += add;
        __syncthreads();
    }
    if (threadIdx.x < nb) bsum[threadIdx.x] = sh[threadIdx.x];
}

__global__ __launch_bounds__(256) void scan_final(const int* __restrict__ tmp, const int* __restrict__ bsum,
                                                  const int* __restrict__ deg, int* __restrict__ offs,
                                                  int* __restrict__ cursor, int n)
{
    int gid = blockIdx.x * 256 + threadIdx.x;
    if (gid >= n) return;
    int b = gid / SCAN_BS;
    int inc = tmp[gid] + (b > 0 ? bsum[b - 1] : 0);
    offs[gid + 1] = inc;
    cursor[gid] = inc - deg[gid];
    if (gid == 0) offs[0] = 0;
}

// csr_fill + pack fused: write packed edge record (src<<9 | bondkey) directly at cursor slot
__global__ __launch_bounds__(256) void csr_fill_pack(
    const int* __restrict__ dst, const int* __restrict__ src, const int* __restrict__ eattr,
    int* __restrict__ cursor, u32* __restrict__ ep, int E)
{
    int e = blockIdx.x * 256 + threadIdx.x;
    if (e < E) {
        int p = atomicAdd(&cursor[dst[e]], 1);
        int key = eattr[e * 3 + 0] + (eattr[e * 3 + 1] << 3) + (eattr[e * 3 + 2] << 6);
        ep[p] = ((u32)src[e] << 9) | (u32)key;
    }
}

// ---------------- aggregation: out_b[n] = bf16( h[n] + sum_{e: dst==n} relu(h[src]+ebtab[key]) ) ----
// 2-way unrolled edge loop: batch ep loads + independent gathers to overlap L2/L3 latency.
__global__ __launch_bounds__(192) void aggregate(
    const u16* __restrict__ h, const u16* __restrict__ ebtab,
    const u32* __restrict__ ep, const int* __restrict__ offs,
    u16* __restrict__ out)
{
    long n = blockIdx.x;
    int t = threadIdx.x;           // 192 threads x 4 cols = 768
    int d = t * 4;
    ushort4 a = *reinterpret_cast<const ushort4*>(h + n * DM + d);
    float acc0 = bf2f(a.x), acc1 = bf2f(a.y), acc2 = bf2f(a.z), acc3 = bf2f(a.w);
    int beg = offs[n], end = offs[n + 1];
    int k = beg;
    for (; k + 2 <= end; k += 2) {
        u32 p0 = ep[k], p1 = ep[k + 1];
        const u16* h0 = h + (long)(p0 >> 9) * DM + d;
        const u16* e0 = ebtab + (long)(p0 & 511) * DM + d;
        const u16* h1 = h + (long)(p1 >> 9) * DM + d;
        const u16* e1 = ebtab + (long)(p1 & 511) * DM + d;
        ushort4 ha = *reinterpret_cast<const ushort4*>(h0);
        ushort4 ea = *reinterpret_cast<const ushort4*>(e0);
        ushort4 hc = *reinterpret_cast<const ushort4*>(h1);
        ushort4 ec = *reinterpret_cast<const ushort4*>(e1);
        acc0 += fmaxf(0.f, bf2f(ha.x) + bf2f(ea.x)) + fmaxf(0.f, bf2f(hc.x) + bf2f(ec.x));
        acc1 += fmaxf(0.f, bf2f(ha.y) + bf2f(ea.y)) + fmaxf(0.f, bf2f(hc.y) + bf2f(ec.y));
        acc2 += fmaxf(0.f, bf2f(ha.z) + bf2f(ea.z)) + fmaxf(0.f, bf2f(hc.z) + bf2f(ec.z));
        acc3 += fmaxf(0.f, bf2f(ha.w) + bf2f(ea.w)) + fmaxf(0.f, bf2f(hc.w) + bf2f(ec.w));
    }
    if (k < end) {
        u32 p0 = ep[k];
        const u16* h0 = h + (long)(p0 >> 9) * DM + d;
        const u16* e0 = ebtab + (long)(p0 & 511) * DM + d;
        ushort4 ha = *reinterpret_cast<const ushort4*>(h0);
        ushort4 ea = *reinterpret_cast<const ushort4*>(e0);
        acc0 += fmaxf(0.f, bf2f(ha.x) + bf2f(ea.x));
        acc1 += fmaxf(0.f, bf2f(ha.y) + bf2f(ea.y));
        acc2 += fmaxf(0.f, bf2f(ha.z) + bf2f(ea.z));
        acc3 += fmaxf(0.f, bf2f(ha.w) + bf2f(ea.w));
    }
    ushort4 o;
    o.x = f2bf(acc0); o.y = f2bf(acc1); o.z = f2bf(acc2); o.w = f2bf(acc3);
    *reinterpret_cast<ushort4*>(out + n * DM + d) = o;
}

// ---------------- GEMM: C[M,768] = act(A[M,768] @ W + bias), bf16 out ----------------
// ACT: 0 none, 1 relu, 2 gelu.
// Best measured structure (r11/r14): 4 waves, triple-buffered LDS, prefetch distance 2,
// counted vmcnt(4) + lgkmcnt(0) fused with s_barrier; s_setprio around MFMA cluster.
union GemmSmem {
    u16 tiles[3][2][128 * 32];   // 48 KB  [buf][A/B][row*32+k]
    u16 ctile[128 * 136];        // epilogue re-stage, padded stride
};

template <int ACT>
__global__ __launch_bounds__(256) void gemm128(
    const u16* __restrict__ A, const u16* __restrict__ Bt,
    const float* __restrict__ bias, u16* __restrict__ outB)
{
    __shared__ GemmSmem sm;
    const int tid = threadIdx.x;
    const int lane = tid & 63, wid = tid >> 6;
    const int wr = wid >> 1, wc = wid & 1;

    // XCD-chunked bijective block swizzle (m204)
    const int nwg = gridDim.x;
    const int orig = blockIdx.x;
    const int q8 = nwg >> 3, r8 = nwg & 7;
    const int xcd = orig & 7, idx8 = orig >> 3;
    const int w = (xcd < r8 ? xcd * (q8 + 1) : r8 * (q8 + 1) + (xcd - r8) * q8) + idx8;
    const int n0 = (w % 6) * 128;
    const long m0 = (long)(w / 6) * 128;

    f32x4 acc[4][4] = {};

    const int ch0 = tid, ch1 = 256 + tid;
    const int r0_ = ch0 >> 2, k0_ = (ch0 & 3) ^ ((r0_ >> 1) & 3);
    const int r1_ = ch1 >> 2, k1_ = (ch1 & 3) ^ ((r1_ >> 1) & 3);
    const u16* Ag0 = A + (m0 + r0_) * DM + k0_ * 8;
    const u16* Ag1 = A + (m0 + r1_) * DM + k1_ * 8;
    const u16* Bg0 = Bt + (long)(n0 + r0_) * DM + k0_ * 8;
    const u16* Bg1 = Bt + (long)(n0 + r1_) * DM + k1_ * 8;
    const int lds0 = ((wid << 6)) * 8;
    const int lds1 = (256 + (wid << 6)) * 8;

    auto stage = [&](int buf, int kt) {
        int ko = kt * 32;
        __builtin_amdgcn_global_load_lds((gvoid*)(Ag0 + ko), (lvoid*)&sm.tiles[buf][0][lds0], 16, 0, 0);
        __builtin_amdgcn_global_load_lds((gvoid*)(Ag1 + ko), (lvoid*)&sm.tiles[buf][0][lds1], 16, 0, 0);
        __builtin_amdgcn_global_load_lds((gvoid*)(Bg0 + ko), (lvoid*)&sm.tiles[buf][1][lds0], 16, 0, 0);
        __builtin_amdgcn_global_load_lds((gvoid*)(Bg1 + ko), (lvoid*)&sm.tiles[buf][1][lds1], 16, 0, 0);
    };

    // prologue: 2 tiles in flight; wait only for tile 0
    stage(0, 0);
    stage(1, 1);
    asm volatile("s_waitcnt vmcnt(4) lgkmcnt(0)\n\ts_barrier" ::: "memory");

    const int ar = lane & 15, kb = lane >> 4;
    const int kbe = kb ^ ((ar >> 1) & 3);
    const int NT = DM / 32;      // 24
    #pragma unroll
    for (int kt = 0; kt < NT; ++kt) {
        const int buf = kt % 3;
        if (kt + 2 < NT) stage((kt + 2) % 3, kt + 2);
        bf16x8 af[4], bv[4];
        #pragma unroll
        for (int m = 0; m < 4; m++)
            af[m] = *reinterpret_cast<const bf16x8*>(&sm.tiles[buf][0][(wr * 64 + m * 16 + ar) * 32 + kbe * 8]);
        #pragma unroll
        for (int n = 0; n < 4; n++)
            bv[n] = *reinterpret_cast<const bf16x8*>(&sm.tiles[buf][1][(wc * 64 + n * 16 + ar) * 32 + kbe * 8]);
        __builtin_amdgcn_s_setprio(1);
        #pragma unroll
        for (int m = 0; m < 4; m++)
            #pragma unroll
            for (int n = 0; n < 4; n++)
                acc[m][n] = __builtin_amdgcn_mfma_f32_16x16x32_bf16(af[m], bv[n], acc[m][n], 0, 0, 0);
        __builtin_amdgcn_s_setprio(0);
        // lgkmcnt(0) REQUIRED before s_barrier (WAR on rotating buffers — round-10 lesson)
        if (kt < NT - 2) {
            asm volatile("s_waitcnt vmcnt(4) lgkmcnt(0)\n\ts_barrier" ::: "memory");
        } else if (kt == NT - 2) {
            asm volatile("s_waitcnt vmcnt(0) lgkmcnt(0)\n\ts_barrier" ::: "memory");
        }
    }
    __syncthreads();   // all waves done reading tiles before ctile overwrites them

    const int rg4 = (lane >> 4) * 4;
    #pragma unroll
    for (int n = 0; n < 4; n++) {
        int lc = wc * 64 + n * 16 + ar;
        float bvp = bias[n0 + lc];
        #pragma unroll
        for (int m = 0; m < 4; m++) {
            int lr = wr * 64 + m * 16 + rg4;
            #pragma unroll
            for (int j = 0; j < 4; j++) {
                float v = acc[m][n][j] + bvp;
                if (ACT == 1) v = fmaxf(v, 0.f);
                if (ACT == 2) v = gelu_f(v);
                sm.ctile[(lr + j) * 136 + lc] = f2bf(v);
            }
        }
    }
    __syncthreads();
    // full-line stores: 4 consecutive lanes write 64B contiguous per instruction
    const int row = tid >> 2, b4 = tid & 3;
    #pragma unroll
    for (int ps = 0; ps < 2; ps++) {
        int rr = row + ps * 64;
        const u16* srcp = &sm.ctile[rr * 136];
        u16* dstp = outB + (m0 + rr) * DM + n0;
        #pragma unroll
        for (int i = 0; i < 4; i++) {
            int c = b4 * 8 + i * 32;
            *reinterpret_cast<uint4*>(dstp + c) = *reinterpret_cast<const uint4*>(srcp + c);
        }
    }
}

extern "C" void kernel_launch(void* const* d_in, const int* in_sizes, int n_in,
                              void* d_out, int out_size, void* d_ws, size_t ws_size,
                              hipStream_t stream)
{
    const int N = in_sizes[0] / 9;
    const int E = in_sizes[1] / 3;
    const int L = 4;
    const long Mpad = ((N + 127) / 128) * 128;
    const int Mtiles = (int)(Mpad / 128);

    const int* x = (const int*)d_in[0];
    const int* eattr = (const int*)d_in[1];
    const int* eidx = (const int*)d_in[2];
    const float* atom_emb = (const float*)d_in[3];
    const float* atom_g = (const float*)d_in[4];
    const float* atom_bb = (const float*)d_in[5];
    const float* atom_w1 = (const float*)d_in[6];
    const float* atom_b1 = (const float*)d_in[7];
    const float* atom_w2 = (const float*)d_in[8];
    const float* atom_b2 = (const float*)d_in[9];
    const float* bond_emb = (const float*)d_in[10];
    const float* bond_g = (const float*)d_in[11];
    const float* bond_bb = (const float*)d_in[12];
    const float* bond_w1 = (const float*)d_in[13];
    const float* bond_b1 = (const float*)d_in[14];
    const float* bond_w2 = (const float*)d_in[15];
    const float* bond_b2 = (const float*)d_in[16];
    const float* conv_w1 = (const float*)d_in[17];
    const float* conv_b1 = (const float*)d_in[18];
    const float* conv_w2 = (const float*)d_in[19];
    const float* conv_b2 = (const float*)d_in[20];
    const float* ln_g = (const float*)d_in[21];
    const float* ln_b = (const float*)d_in[22];
    const int* src = eidx;
    const int* dst = eidx + E;
    float* dout = (float*)d_out;

    char* p = (char*)d_ws;
    auto alloc = [&](size_t bytes) { void* r = (void*)p; p += (bytes + 255) & ~(size_t)255; return r; };
    u16* B2   = (u16*)alloc((size_t)2 * Mpad * DM * 2);   // node bf16 ping-pong
    u16* h_b  = (u16*)alloc((size_t)Mpad * DM * 2);
    u16* wbt  = (u16*)alloc((size_t)12 * DM * DM * 2);
    u16* bt0  = (u16*)alloc((size_t)512 * DM * 2);
    u16* bt1  = (u16*)alloc((size_t)512 * DM * 2);
    u16* ebtab= (u16*)alloc((size_t)512 * DM * 2);
    int* deg    = (int*)alloc((size_t)N * 4);
    int* tmp    = (int*)alloc((size_t)N * 4);
    int* cursor = (int*)alloc((size_t)N * 4);
    int* offs   = (int*)alloc((size_t)(N + 1) * 4);
    int* bsum   = (int*)alloc((size_t)SCAN_BS * 4);
    u32* ep     = (u32*)alloc((size_t)E * 4);
    u16* B2a = B2;
    u16* B2b = B2 + (size_t)Mpad * DM;

    // ---- CSR build (counting sort by dst), packed edge records written directly ----
    hipMemsetAsync(deg, 0, (size_t)N * 4, stream);
    csr_count<<<(E + 255) / 256, 256, 0, stream>>>(dst, deg, E);
    const int nb = (N + SCAN_BS - 1) / SCAN_BS;
    scan_block<<<nb, SCAN_BS, 0, stream>>>(deg, tmp, bsum, N);
    scan_bsum<<<1, SCAN_BS, 0, stream>>>(bsum, nb);
    scan_final<<<(N + 255) / 256, 256, 0, stream>>>(tmp, bsum, deg, offs, cursor, N);
    csr_fill_pack<<<(E + 255) / 256, 256, 0, stream>>>(dst, src, eattr, cursor, ep, E);

    // weight prep (12 matrices, transpose + bf16)
    prep_weights<<<dim3(24, 24, 12), 256, 0, stream>>>(atom_w1, atom_w2, bond_w1, bond_w2, conv_w1, conv_w2, wbt);

    // bond encoder on the 512-key table only
    encode_ln_bond<<<512, 256, 0, stream>>>(bond_emb, bond_g, bond_bb, bt0);
    gemm128<2><<<6 * 4, 256, 0, stream>>>(bt0, wbt + (size_t)2 * DM * DM, bond_b1, bt1);
    gemm128<0><<<6 * 4, 256, 0, stream>>>(bt1, wbt + (size_t)3 * DM * DM, bond_b2, ebtab);

    // atom encoder: emb-sum+LN -> B2a; GEMM1(gelu) B2a->B2b; GEMM2 -> h_b bf16
    encode_ln9<<<N, 192, 0, stream>>>(x, atom_emb, atom_g, atom_bb, B2a);
    gemm128<2><<<6 * Mtiles, 256, 0, stream>>>(B2a, wbt + (size_t)0 * DM * DM, atom_b1, B2b);
    gemm128<0><<<6 * Mtiles, 256, 0, stream>>>(B2b, wbt + (size_t)1 * DM * DM, atom_b2, h_b);

    // GNN layers: aggregate -> GEMM1(relu) -> GEMM2(gelu, bf16 y) -> LN(residual)
    for (int l = 0; l < L; l++) {
        aggregate<<<N, 192, 0, stream>>>(h_b, ebtab, ep, offs, B2a);
        gemm128<1><<<6 * Mtiles, 256, 0, stream>>>(B2a, wbt + (size_t)(4 + l) * DM * DM, conv_b1 + l * DM, B2b);
        gemm128<2><<<6 * Mtiles, 256, 0, stream>>>(B2b, wbt + (size_t)(8 + l) * DM * DM, conv_b2 + l * DM, B2a);
        layer_ln<<<N, 192, 0, stream>>>(B2a, h_b, ln_g + l * DM, ln_b + l * DM,
                                        h_b, (l == L - 1) ? dout : nullptr);
    }
}

// Round 18
// 2638.403 us; speedup vs baseline: 1.0030x; 1.0030x over previous
//
#include <hip/hip_runtime.h>

#define DM 768
#define SCAN_BS 1024

using u16 = unsigned short;
using u32 = unsigned int;

typedef __attribute__((ext_vector_type(8))) __bf16 bf16x8;
typedef __attribute__((ext_vector_type(4))) float f32x4;
typedef __attribute__((address_space(1))) void gvoid;
typedef __attribute__((address_space(3))) void lvoid;

__device__ __forceinline__ float bf2f(u16 h) { return __uint_as_float(((u32)h) << 16); }
__device__ __forceinline__ u16 f2bf(float f) {
    u32 u = __float_as_uint(f);
    u32 r = (u + 0x7FFFu + ((u >> 16) & 1u)) >> 16;
    return (u16)r;
}
// tanh-form GELU (max |err| vs exact erf-GELU ~1e-3): cheap v_exp + rcp
__device__ __forceinline__ float gelu_f(float x) {
    float y = 0.7978845608f * x * (1.f + 0.044715f * x * x);
    float e = __expf(2.f * y);
    float th = 1.f - 2.f * __builtin_amdgcn_rcpf(e + 1.f);   // tanh(y), inf-safe
    return 0.5f * x * (1.f + th);
}

// ---------------- weight prep: W[768,768] f32 -> Wt[768,768] bf16 (transposed) ----------------
__global__ __launch_bounds__(256) void prep_weights(
    const float* __restrict__ aw1, const float* __restrict__ aw2,
    const float* __restrict__ bw1, const float* __restrict__ bw2,
    const float* __restrict__ cw1, const float* __restrict__ cw2,
    u16* __restrict__ wbt)
{
    int z = blockIdx.z;
    const float* W;
    if (z == 0) W = aw1;
    else if (z == 1) W = aw2;
    else if (z == 2) W = bw1;
    else if (z == 3) W = bw2;
    else if (z < 8) W = cw1 + (size_t)(z - 4) * DM * DM;
    else W = cw2 + (size_t)(z - 8) * DM * DM;
    u16* out = wbt + (size_t)z * DM * DM;

    __shared__ float tile[32][33];
    int bx = blockIdx.x * 32, by = blockIdx.y * 32;
    int tx = threadIdx.x & 31, ty = threadIdx.x >> 5;
    #pragma unroll
    for (int i = ty; i < 32; i += 8) tile[i][tx] = W[(size_t)(by + i) * DM + bx + tx];
    __syncthreads();
    #pragma unroll
    for (int i = ty; i < 32; i += 8) out[(size_t)(bx + i) * DM + by + tx] = f2bf(tile[tx][i]);
}

// ---------------- atom embedding (nf=9, vocab=64 hard-coded): sum + LN -> bf16 ----------------
__global__ __launch_bounds__(192) void encode_ln9(
    const int* __restrict__ idx,
    const float* __restrict__ emb, const float* __restrict__ g, const float* __restrict__ bb,
    u16* __restrict__ out)
{
    long n = blockIdx.x;
    int t = threadIdx.x;            // 192 threads x 4 cols
    int d = t * 4;
    __shared__ int feat[12];
    __shared__ float sred[8];
    if (t < 9) feat[t] = idx[n * 9 + t];
    __syncthreads();
    float a0 = 0.f, a1 = 0.f, a2 = 0.f, a3 = 0.f;
    #pragma unroll
    for (int f = 0; f < 9; f++) {
        const float* rp = emb + (size_t)f * 64 * DM + (size_t)feat[f] * DM + d;
        float4 v = *reinterpret_cast<const float4*>(rp);
        a0 += v.x; a1 += v.y; a2 += v.z; a3 += v.w;
    }
    float s = a0 + a1 + a2 + a3;
    float s2 = a0 * a0 + a1 * a1 + a2 * a2 + a3 * a3;
    #pragma unroll
    for (int o = 32; o; o >>= 1) { s += __shfl_down(s, o); s2 += __shfl_down(s2, o); }
    int wid = t >> 6;
    if ((t & 63) == 0) { sred[wid] = s; sred[4 + wid] = s2; }
    __syncthreads();
    float S = sred[0] + sred[1] + sred[2];
    float S2 = sred[4] + sred[5] + sred[6];
    float mean = S * (1.f / 768.f);
    float var = S2 * (1.f / 768.f) - mean * mean;
    float rstd = rsqrtf(var + 1e-5f);
    ushort4 o;
    o.x = f2bf((a0 - mean) * rstd * g[d + 0] + bb[d + 0]);
    o.y = f2bf((a1 - mean) * rstd * g[d + 1] + bb[d + 1]);
    o.z = f2bf((a2 - mean) * rstd * g[d + 2] + bb[d + 2]);
    o.w = f2bf((a3 - mean) * rstd * g[d + 3] + bb[d + 3]);
    *reinterpret_cast<ushort4*>(out + n * DM + d) = o;
}

// ---------------- bond table: all 512 key combos, emb-sum + LN -> bf16 ----------------
__global__ __launch_bounds__(256) void encode_ln_bond(
    const float* __restrict__ emb, const float* __restrict__ g, const float* __restrict__ bb,
    u16* __restrict__ out)
{
    int key = blockIdx.x;       // 0..511
    int t = threadIdx.x;
    __shared__ float sred[16];
    int f0 = key & 7, f1 = (key >> 3) & 7, f2 = (key >> 6) & 7;
    float v[3];
    float s = 0.f, s2 = 0.f;
    #pragma unroll
    for (int j = 0; j < 3; j++) {
        int d = t + j * 256;
        float a = emb[(0 * 8 + f0) * DM + d] + emb[(1 * 8 + f1) * DM + d] + emb[(2 * 8 + f2) * DM + d];
        v[j] = a; s += a; s2 += a * a;
    }
    #pragma unroll
    for (int o = 32; o; o >>= 1) { s += __shfl_down(s, o); s2 += __shfl_down(s2, o); }
    int wid = t >> 6;
    if ((t & 63) == 0) { sred[wid] = s; sred[8 + wid] = s2; }
    __syncthreads();
    if (t == 0) {
        sred[0] = sred[0] + sred[1] + sred[2] + sred[3];
        sred[8] = sred[8] + sred[9] + sred[10] + sred[11];
    }
    __syncthreads();
    float mean = sred[0] * (1.f / 768.f);
    float var = sred[8] * (1.f / 768.f) - mean * mean;
    float rstd = rsqrtf(var + 1e-5f);
    #pragma unroll
    for (int j = 0; j < 3; j++) {
        int d = t + j * 256;
        out[(long)key * DM + d] = f2bf((v[j] - mean) * rstd * g[d] + bb[d]);
    }
}

// ---------------- post-layer: t = y(bf16) + h_old(bf16); LN; write h_b OR final f32 out ----------------
__global__ __launch_bounds__(192) void layer_ln(
    const u16* __restrict__ y, const u16* __restrict__ holdb,
    const float* __restrict__ g, const float* __restrict__ bb,
    u16* __restrict__ hb, float* __restrict__ dout)
{
    long n = blockIdx.x;
    int t = threadIdx.x;           // 192 threads x 4 cols = 768
    int d = t * 4;
    __shared__ float sred[8];
    ushort4 yv = *reinterpret_cast<const ushort4*>(y + n * DM + d);
    ushort4 hv = *reinterpret_cast<const ushort4*>(holdb + n * DM + d);
    float v0 = bf2f(yv.x) + bf2f(hv.x);
    float v1 = bf2f(yv.y) + bf2f(hv.y);
    float v2 = bf2f(yv.z) + bf2f(hv.z);
    float v3 = bf2f(yv.w) + bf2f(hv.w);
    float s = v0 + v1 + v2 + v3;
    float s2 = v0 * v0 + v1 * v1 + v2 * v2 + v3 * v3;
    #pragma unroll
    for (int o = 32; o; o >>= 1) { s += __shfl_down(s, o); s2 += __shfl_down(s2, o); }
    int wid = t >> 6;
    if ((t & 63) == 0) { sred[wid] = s; sred[4 + wid] = s2; }
    __syncthreads();
    float S = sred[0] + sred[1] + sred[2];
    float S2 = sred[4] + sred[5] + sred[6];
    float mean = S * (1.f / 768.f);
    float var = S2 * (1.f / 768.f) - mean * mean;
    float rstd = rsqrtf(var + 1e-5f);
    float r0 = (v0 - mean) * rstd * g[d + 0] + bb[d + 0];
    float r1 = (v1 - mean) * rstd * g[d + 1] + bb[d + 1];
    float r2 = (v2 - mean) * rstd * g[d + 2] + bb[d + 2];
    float r3 = (v3 - mean) * rstd * g[d + 3] + bb[d + 3];
    if (dout) {
        float4 o = { r0, r1, r2, r3 };
        *reinterpret_cast<float4*>(dout + n * DM + d) = o;
    } else {
        ushort4 o;
        o.x = f2bf(r0); o.y = f2bf(r1); o.z = f2bf(r2); o.w = f2bf(r3);
        *reinterpret_cast<ushort4*>(hb + n * DM + d) = o;
    }
}

// ---------------- CSR build: counting sort of edges by dst ----------------
__global__ __launch_bounds__(256) void csr_count(const int* __restrict__ dst, int* __restrict__ deg, int E)
{
    int e = blockIdx.x * 256 + threadIdx.x;
    if (e < E) atomicAdd(&deg[dst[e]], 1);
}

__global__ __launch_bounds__(SCAN_BS) void scan_block(const int* __restrict__ deg, int* __restrict__ tmp,
                                                      int* __restrict__ bsum, int n)
{
    __shared__ int sh[SCAN_BS];
    int gid = blockIdx.x * SCAN_BS + threadIdx.x;
    int v = (gid < n) ? deg[gid] : 0;
    sh[threadIdx.x] = v;
    __syncthreads();
    for (int o = 1; o < SCAN_BS; o <<= 1) {
        int add = (threadIdx.x >= o) ? sh[threadIdx.x - o] : 0;
        __syncthreads();
        sh[threadIdx.x] += add;
        __syncthreads();
    }
    if (gid < n) tmp[gid] = sh[threadIdx.x];
    if (threadIdx.x == SCAN_BS - 1) bsum[blockIdx.x] = sh[SCAN_BS - 1];
}

__global__ __launch_bounds__(SCAN_BS) void scan_bsum(int* __restrict__ bsum, int nb)
{
    __shared__ int sh[SCAN_BS];
    int v = (threadIdx.x < nb) ? bsum[threadIdx.x] : 0;
    sh[threadIdx.x] = v;
    __syncthreads();
    for (int o = 1; o < SCAN_BS; o <<= 1) {
        int add = (threadIdx.x >= o) ? sh[threadIdx.x - o] : 0;
        __syncthreads();
        sh[threadIdx.x] += add;
        __syncthreads();
    }
    if (threadIdx.x < nb) bsum[threadIdx.x] = sh[threadIdx.x];
}

__global__ __launch_bounds__(256) void scan_final(const int* __restrict__ tmp, const int* __restrict__ bsum,
                                                  const int* __restrict__ deg, int* __restrict__ offs,
                                                  int* __restrict__ cursor, int n)
{
    int gid = blockIdx.x * 256 + threadIdx.x;
    if (gid >= n) return;
    int b = gid / SCAN_BS;
    int inc = tmp[gid] + (b > 0 ? bsum[b - 1] : 0);
    offs[gid + 1] = inc;
    cursor[gid] = inc - deg[gid];
    if (gid == 0) offs[0] = 0;
}

// csr_fill + pack fused: write packed edge record (src<<9 | bondkey) directly at cursor slot
__global__ __launch_bounds__(256) void csr_fill_pack(
    const int* __restrict__ dst, const int* __restrict__ src, const int* __restrict__ eattr,
    int* __restrict__ cursor, u32* __restrict__ ep, int E)
{
    int e = blockIdx.x * 256 + threadIdx.x;
    if (e < E) {
        int p = atomicAdd(&cursor[dst[e]], 1);
        int key = eattr[e * 3 + 0] + (eattr[e * 3 + 1] << 3) + (eattr[e * 3 + 2] << 6);
        ep[p] = ((u32)src[e] << 9) | (u32)key;
    }
}

// ---------------- aggregation: out_b[n] = bf16( h[n] + sum_{e: dst==n} relu(h[src]+ebtab[key]) ) ----
// 2-way unrolled edge loop: batch ep loads + independent gathers to overlap L2/L3 latency.
__global__ __launch_bounds__(192) void aggregate(
    const u16* __restrict__ h, const u16* __restrict__ ebtab,
    const u32* __restrict__ ep, const int* __restrict__ offs,
    u16* __restrict__ out)
{
    long n = blockIdx.x;
    int t = threadIdx.x;           // 192 threads x 4 cols = 768
    int d = t * 4;
    ushort4 a = *reinterpret_cast<const ushort4*>(h + n * DM + d);
    float acc0 = bf2f(a.x), acc1 = bf2f(a.y), acc2 = bf2f(a.z), acc3 = bf2f(a.w);
    int beg = offs[n], end = offs[n + 1];
    int k = beg;
    for (; k + 2 <= end; k += 2) {
        u32 p0 = ep[k], p1 = ep[k + 1];
        const u16* h0 = h + (long)(p0 >> 9) * DM + d;
        const u16* e0 = ebtab + (long)(p0 & 511) * DM + d;
        const u16* h1 = h + (long)(p1 >> 9) * DM + d;
        const u16* e1 = ebtab + (long)(p1 & 511) * DM + d;
        ushort4 ha = *reinterpret_cast<const ushort4*>(h0);
        ushort4 ea = *reinterpret_cast<const ushort4*>(e0);
        ushort4 hc = *reinterpret_cast<const ushort4*>(h1);
        ushort4 ec = *reinterpret_cast<const ushort4*>(e1);
        acc0 += fmaxf(0.f, bf2f(ha.x) + bf2f(ea.x)) + fmaxf(0.f, bf2f(hc.x) + bf2f(ec.x));
        acc1 += fmaxf(0.f, bf2f(ha.y) + bf2f(ea.y)) + fmaxf(0.f, bf2f(hc.y) + bf2f(ec.y));
        acc2 += fmaxf(0.f, bf2f(ha.z) + bf2f(ea.z)) + fmaxf(0.f, bf2f(hc.z) + bf2f(ec.z));
        acc3 += fmaxf(0.f, bf2f(ha.w) + bf2f(ea.w)) + fmaxf(0.f, bf2f(hc.w) + bf2f(ec.w));
    }
    if (k < end) {
        u32 p0 = ep[k];
        const u16* h0 = h + (long)(p0 >> 9) * DM + d;
        const u16* e0 = ebtab + (long)(p0 & 511) * DM + d;
        ushort4 ha = *reinterpret_cast<const ushort4*>(h0);
        ushort4 ea = *reinterpret_cast<const ushort4*>(e0);
        acc0 += fmaxf(0.f, bf2f(ha.x) + bf2f(ea.x));
        acc1 += fmaxf(0.f, bf2f(ha.y) + bf2f(ea.y));
        acc2 += fmaxf(0.f, bf2f(ha.z) + bf2f(ea.z));
        acc3 += fmaxf(0.f, bf2f(ha.w) + bf2f(ea.w));
    }
    ushort4 o;
    o.x = f2bf(acc0); o.y = f2bf(acc1); o.z = f2bf(acc2); o.w = f2bf(acc3);
    *reinterpret_cast<ushort4*>(out + n * DM + d) = o;
}

// ---------------- GEMM: C[M,768] = act(A[M,768] @ W + bias), bf16 out ----------------
// ACT: 0 none, 1 relu, 2 gelu.
// Best measured structure (r11/r14): 4 waves, triple-buffered LDS, prefetch distance 2,
// counted vmcnt(4) + lgkmcnt(0) fused with s_barrier; s_setprio around MFMA cluster.
union GemmSmem {
    u16 tiles[3][2][128 * 32];   // 48 KB  [buf][A/B][row*32+k]
    u16 ctile[128 * 136];        // epilogue re-stage, padded stride
};

template <int ACT>
__global__ __launch_bounds__(256) void gemm128(
    const u16* __restrict__ A, const u16* __restrict__ Bt,
    const float* __restrict__ bias, u16* __restrict__ outB)
{
    __shared__ GemmSmem sm;
    const int tid = threadIdx.x;
    const int lane = tid & 63, wid = tid >> 6;
    const int wr = wid >> 1, wc = wid & 1;

    // XCD-chunked bijective block swizzle (m204)
    const int nwg = gridDim.x;
    const int orig = blockIdx.x;
    const int q8 = nwg >> 3, r8 = nwg & 7;
    const int xcd = orig & 7, idx8 = orig >> 3;
    const int w = (xcd < r8 ? xcd * (q8 + 1) : r8 * (q8 + 1) + (xcd - r8) * q8) + idx8;
    const int n0 = (w % 6) * 128;
    const long m0 = (long)(w / 6) * 128;

    f32x4 acc[4][4] = {};

    const int ch0 = tid, ch1 = 256 + tid;
    const int r0_ = ch0 >> 2, k0_ = (ch0 & 3) ^ ((r0_ >> 1) & 3);
    const int r1_ = ch1 >> 2, k1_ = (ch1 & 3) ^ ((r1_ >> 1) & 3);
    const u16* Ag0 = A + (m0 + r0_) * DM + k0_ * 8;
    const u16* Ag1 = A + (m0 + r1_) * DM + k1_ * 8;
    const u16* Bg0 = Bt + (long)(n0 + r0_) * DM + k0_ * 8;
    const u16* Bg1 = Bt + (long)(n0 + r1_) * DM + k1_ * 8;
    const int lds0 = ((wid << 6)) * 8;
    const int lds1 = (256 + (wid << 6)) * 8;

    auto stage = [&](int buf, int kt) {
        int ko = kt * 32;
        __builtin_amdgcn_global_load_lds((gvoid*)(Ag0 + ko), (lvoid*)&sm.tiles[buf][0][lds0], 16, 0, 0);
        __builtin_amdgcn_global_load_lds((gvoid*)(Ag1 + ko), (lvoid*)&sm.tiles[buf][0][lds1], 16, 0, 0);
        __builtin_amdgcn_global_load_lds((gvoid*)(Bg0 + ko), (lvoid*)&sm.tiles[buf][1][lds0], 16, 0, 0);
        __builtin_amdgcn_global_load_lds((gvoid*)(Bg1 + ko), (lvoid*)&sm.tiles[buf][1][lds1], 16, 0, 0);
    };

    // prologue: 2 tiles in flight; wait only for tile 0
    stage(0, 0);
    stage(1, 1);
    asm volatile("s_waitcnt vmcnt(4) lgkmcnt(0)\n\ts_barrier" ::: "memory");

    const int ar = lane & 15, kb = lane >> 4;
    const int kbe = kb ^ ((ar >> 1) & 3);
    const int NT = DM / 32;      // 24
    #pragma unroll
    for (int kt = 0; kt < NT; ++kt) {
        const int buf = kt % 3;
        if (kt + 2 < NT) stage((kt + 2) % 3, kt + 2);
        bf16x8 af[4], bv[4];
        #pragma unroll
        for (int m = 0; m < 4; m++)
            af[m] = *reinterpret_cast<const bf16x8*>(&sm.tiles[buf][0][(wr * 64 + m * 16 + ar) * 32 + kbe * 8]);
        #pragma unroll
        for (int n = 0; n < 4; n++)
            bv[n] = *reinterpret_cast<const bf16x8*>(&sm.tiles[buf][1][(wc * 64 + n * 16 + ar) * 32 + kbe * 8]);
        __builtin_amdgcn_s_setprio(1);
        #pragma unroll
        for (int m = 0; m < 4; m++)
            #pragma unroll
            for (int n = 0; n < 4; n++)
                acc[m][n] = __builtin_amdgcn_mfma_f32_16x16x32_bf16(af[m], bv[n], acc[m][n], 0, 0, 0);
        __builtin_amdgcn_s_setprio(0);
        // lgkmcnt(0) REQUIRED before s_barrier (WAR on rotating buffers — round-10 lesson)
        if (kt < NT - 2) {
            asm volatile("s_waitcnt vmcnt(4) lgkmcnt(0)\n\ts_barrier" ::: "memory");
        } else if (kt == NT - 2) {
            asm volatile("s_waitcnt vmcnt(0) lgkmcnt(0)\n\ts_barrier" ::: "memory");
        }
    }
    __syncthreads();   // all waves done reading tiles before ctile overwrites them

    const int rg4 = (lane >> 4) * 4;
    #pragma unroll
    for (int n = 0; n < 4; n++) {
        int lc = wc * 64 + n * 16 + ar;
        float bvp = bias[n0 + lc];
        #pragma unroll
        for (int m = 0; m < 4; m++) {
            int lr = wr * 64 + m * 16 + rg4;
            #pragma unroll
            for (int j = 0; j < 4; j++) {
                float v = acc[m][n][j] + bvp;
                if (ACT == 1) v = fmaxf(v, 0.f);
                if (ACT == 2) v = gelu_f(v);
                sm.ctile[(lr + j) * 136 + lc] = f2bf(v);
            }
        }
    }
    __syncthreads();
    // full-line stores: 4 consecutive lanes write 64B contiguous per instruction
    const int row = tid >> 2, b4 = tid & 3;
    #pragma unroll
    for (int ps = 0; ps < 2; ps++) {
        int rr = row + ps * 64;
        const u16* srcp = &sm.ctile[rr * 136];
        u16* dstp = outB + (m0 + rr) * DM + n0;
        #pragma unroll
        for (int i = 0; i < 4; i++) {
            int c = b4 * 8 + i * 32;
            *reinterpret_cast<uint4*>(dstp + c) = *reinterpret_cast<const uint4*>(srcp + c);
        }
    }
}

extern "C" void kernel_launch(void* const* d_in, const int* in_sizes, int n_in,
                              void* d_out, int out_size, void* d_ws, size_t ws_size,
                              hipStream_t stream)
{
    const int N = in_sizes[0] / 9;
    const int E = in_sizes[1] / 3;
    const int L = 4;
    const long Mpad = ((N + 127) / 128) * 128;
    const int Mtiles = (int)(Mpad / 128);

    const int* x = (const int*)d_in[0];
    const int* eattr = (const int*)d_in[1];
    const int* eidx = (const int*)d_in[2];
    const float* atom_emb = (const float*)d_in[3];
    const float* atom_g = (const float*)d_in[4];
    const float* atom_bb = (const float*)d_in[5];
    const float* atom_w1 = (const float*)d_in[6];
    const float* atom_b1 = (const float*)d_in[7];
    const float* atom_w2 = (const float*)d_in[8];
    const float* atom_b2 = (const float*)d_in[9];
    const float* bond_emb = (const float*)d_in[10];
    const float* bond_g = (const float*)d_in[11];
    const float* bond_bb = (const float*)d_in[12];
    const float* bond_w1 = (const float*)d_in[13];
    const float* bond_b1 = (const float*)d_in[14];
    const float* bond_w2 = (const float*)d_in[15];
    const float* bond_b2 = (const float*)d_in[16];
    const float* conv_w1 = (const float*)d_in[17];
    const float* conv_b1 = (const float*)d_in[18];
    const float* conv_w2 = (const float*)d_in[19];
    const float* conv_b2 = (const float*)d_in[20];
    const float* ln_g = (const float*)d_in[21];
    const float* ln_b = (const float*)d_in[22];
    const int* src = eidx;
    const int* dst = eidx + E;
    float* dout = (float*)d_out;

    char* p = (char*)d_ws;
    auto alloc = [&](size_t bytes) { void* r = (void*)p; p += (bytes + 255) & ~(size_t)255; return r; };
    u16* B2   = (u16*)alloc((size_t)2 * Mpad * DM * 2);   // node bf16 ping-pong
    u16* h_b  = (u16*)alloc((size_t)Mpad * DM * 2);
    u16* wbt  = (u16*)alloc((size_t)12 * DM * DM * 2);
    u16* bt0  = (u16*)alloc((size_t)512 * DM * 2);
    u16* bt1  = (u16*)alloc((size_t)512 * DM * 2);
    u16* ebtab= (u16*)alloc((size_t)512 * DM * 2);
    int* deg    = (int*)alloc((size_t)N * 4);
    int* tmp    = (int*)alloc((size_t)N * 4);
    int* cursor = (int*)alloc((size_t)N * 4);
    int* offs   = (int*)alloc((size_t)(N + 1) * 4);
    int* bsum   = (int*)alloc((size_t)SCAN_BS * 4);
    u32* ep     = (u32*)alloc((size_t)E * 4);
    u16* B2a = B2;
    u16* B2b = B2 + (size_t)Mpad * DM;

    // ---- CSR build (counting sort by dst), packed edge records written directly ----
    hipMemsetAsync(deg, 0, (size_t)N * 4, stream);
    csr_count<<<(E + 255) / 256, 256, 0, stream>>>(dst, deg, E);
    const int nb = (N + SCAN_BS - 1) / SCAN_BS;
    scan_block<<<nb, SCAN_BS, 0, stream>>>(deg, tmp, bsum, N);
    scan_bsum<<<1, SCAN_BS, 0, stream>>>(bsum, nb);
    scan_final<<<(N + 255) / 256, 256, 0, stream>>>(tmp, bsum, deg, offs, cursor, N);
    csr_fill_pack<<<(E + 255) / 256, 256, 0, stream>>>(dst, src, eattr, cursor, ep, E);

    // weight prep (12 matrices, transpose + bf16)
    prep_weights<<<dim3(24, 24, 12), 256, 0, stream>>>(atom_w1, atom_w2, bond_w1, bond_w2, conv_w1, conv_w2, wbt);

    // bond encoder on the 512-key table only
    encode_ln_bond<<<512, 256, 0, stream>>>(bond_emb, bond_g, bond_bb, bt0);
    gemm128<2><<<6 * 4, 256, 0, stream>>>(bt0, wbt + (size_t)2 * DM * DM, bond_b1, bt1);
    gemm128<0><<<6 * 4, 256, 0, stream>>>(bt1, wbt + (size_t)3 * DM * DM, bond_b2, ebtab);

    // atom encoder: emb-sum+LN -> B2a; GEMM1(gelu) B2a->B2b; GEMM2 -> h_b bf16
    encode_ln9<<<N, 192, 0, stream>>>(x, atom_emb, atom_g, atom_bb, B2a);
    gemm128<2><<<6 * Mtiles, 256, 0, stream>>>(B2a, wbt + (size_t)0 * DM * DM, atom_b1, B2b);
    gemm128<0><<<6 * Mtiles, 256, 0, stream>>>(B2b, wbt + (size_t)1 * DM * DM, atom_b2, h_b);

    // GNN layers: aggregate -> GEMM1(relu) -> GEMM2(gelu, bf16 y) -> LN(residual)
    for (int l = 0; l < L; l++) {
        aggregate<<<N, 192, 0, stream>>>(h_b, ebtab, ep, offs, B2a);
        gemm128<1><<<6 * Mtiles, 256, 0, stream>>>(B2a, wbt + (size_t)(4 + l) * DM * DM, conv_b1 + l * DM, B2b);
        gemm128<2><<<6 * Mtiles, 256, 0, stream>>>(B2b, wbt + (size_t)(8 + l) * DM * DM, conv_b2 + l * DM, B2a);
        layer_ln<<<N, 192, 0, stream>>>(B2a, h_b, ln_g + l * DM, ln_b + l * DM,
                                        h_b, (l == L - 1) ? dout : nullptr);
    }
}